// Round 10
// baseline (4952.240 us; speedup 1.0000x reference)
//
#include <hip/hip_runtime.h>
#include <hip/hip_fp16.h>
#include <cstdint>

typedef _Float16 h2 __attribute__((ext_vector_type(2)));
typedef _Float16 h8 __attribute__((ext_vector_type(8)));
typedef float    f2 __attribute__((ext_vector_type(2)));
typedef float    f4 __attribute__((ext_vector_type(4)));
typedef uint32_t u4 __attribute__((ext_vector_type(4)));

#define BATCH 64
#define TSTEPS 1024
#define DDIM 512
#define HDIM 512

static __device__ __forceinline__ float fdot2(uint32_t w, uint32_t h, float acc) {
  return __builtin_amdgcn_fdot2(__builtin_bit_cast(h2, w), __builtin_bit_cast(h2, h), acc, false);
}

// Raw barrier: LDS-ordering only — NO vmcnt drain (xp/out/weight-stream VMEM
// ops stay in flight across barriers). Verified win in r4.
#define BAR_LDS()                                            \
  do {                                                       \
    __builtin_amdgcn_sched_barrier(0);                       \
    asm volatile("s_waitcnt lgkmcnt(0)" ::: "memory");       \
    __builtin_amdgcn_s_barrier();                            \
    __builtin_amdgcn_sched_barrier(0);                       \
  } while (0)

// ---------------------------------------------------------------------------
// prep: f16 weight conversion, pair-transposed Whh, bias sums.
// ---------------------------------------------------------------------------
__global__ void prep_kernel(const float* __restrict__ Wih_f, const float* __restrict__ Whh_f,
                            const float* __restrict__ bih_f, const float* __restrict__ bhh_f,
                            const float* __restrict__ Wih_b, const float* __restrict__ Whh_b,
                            const float* __restrict__ bih_b, const float* __restrict__ bhh_b,
                            _Float16* __restrict__ wi16, uint32_t* __restrict__ whT,
                            float* __restrict__ bsum) {
  int i = blockIdx.x * 256 + threadIdx.x;
  if (i < 2 * 512 * 512) {
    const float* s = (i < 512 * 512) ? Wih_f : Wih_b;
    wi16[i] = (_Float16)s[i & (512 * 512 - 1)];
  }
  if (i < 2 * 256 * 512) {
    int d = i >> 17; int rem = i & ((1 << 17) - 1);
    int kp = rem >> 9; int j = rem & 511;
    const float* W = d ? Whh_b : Whh_f;
    h2 p; p[0] = (_Float16)W[j * 512 + 2 * kp]; p[1] = (_Float16)W[j * 512 + 2 * kp + 1];
    whT[i] = __builtin_bit_cast(uint32_t, p);
  }
  if (i < 2 * 512) {
    int d = i >> 9, j = i & 511;
    bsum[i] = d ? (bih_b[j] + bhh_b[j]) : (bih_f[j] + bhh_f[j]);
  }
}

// ---------------------------------------------------------------------------
// xp_gemm (unchanged): xp[dir][m][n] f16, m = b*1024 + t (processing order).
// ---------------------------------------------------------------------------
__global__ __launch_bounds__(256) void xp_gemm(const float* __restrict__ x,
                                               const _Float16* __restrict__ wi,
                                               const float* __restrict__ bsum,
                                               _Float16* __restrict__ xp) {
  __shared__ _Float16 As[128][40];
  __shared__ _Float16 Bs[128][40];
  const int mt = blockIdx.x, nt = blockIdx.y, dir = blockIdx.z;
  const int m0 = mt * 128, n0 = nt * 128;
  const int tid = threadIdx.x;
  const int lane = tid & 63, w = tid >> 6;
  const int wr = w >> 1, wc = w & 1;
  const int ra = tid >> 1, hf = tid & 1;

  const int mrow = m0 + ra;
  const int bb = mrow >> 10, pp = mrow & 1023;
  const int srow = dir ? ((bb << 10) + (1023 - pp)) : mrow;
  const float*    xbase = x + (size_t)srow * 512 + hf * 16;
  const _Float16* wbase = wi + (size_t)dir * 512 * 512 + (size_t)(n0 + ra) * 512 + hf * 16;

  f4 acc[4][4];
  #pragma unroll
  for (int a = 0; a < 4; ++a)
    #pragma unroll
    for (int b = 0; b < 4; ++b) acc[a][b] = (f4)0.f;

  for (int k0 = 0; k0 < 512; k0 += 32) {
    f4 x0 = *(const f4*)(xbase + k0);
    f4 x1 = *(const f4*)(xbase + k0 + 4);
    f4 x2 = *(const f4*)(xbase + k0 + 8);
    f4 x3 = *(const f4*)(xbase + k0 + 12);
    h8 b0 = *(const h8*)(wbase + k0);
    h8 b1 = *(const h8*)(wbase + k0 + 8);
    h8 a0, a1;
    #pragma unroll
    for (int u = 0; u < 4; ++u) {
      a0[u] = (_Float16)x0[u]; a0[4 + u] = (_Float16)x1[u];
      a1[u] = (_Float16)x2[u]; a1[4 + u] = (_Float16)x3[u];
    }
    __syncthreads();
    *(h8*)&As[ra][hf * 16]     = a0;
    *(h8*)&As[ra][hf * 16 + 8] = a1;
    *(h8*)&Bs[ra][hf * 16]     = b0;
    *(h8*)&Bs[ra][hf * 16 + 8] = b1;
    __syncthreads();
    h8 af[4], bf[4];
    #pragma unroll
    for (int fm = 0; fm < 4; ++fm)
      af[fm] = *(const h8*)&As[wr * 64 + fm * 16 + (lane & 15)][(lane >> 4) * 8];
    #pragma unroll
    for (int fn = 0; fn < 4; ++fn)
      bf[fn] = *(const h8*)&Bs[wc * 64 + fn * 16 + (lane & 15)][(lane >> 4) * 8];
    #pragma unroll
    for (int fm = 0; fm < 4; ++fm)
      #pragma unroll
      for (int fn = 0; fn < 4; ++fn)
        acc[fm][fn] = __builtin_amdgcn_mfma_f32_16x16x32_f16(af[fm], bf[fn], acc[fm][fn], 0, 0, 0);
  }

  float bsv[4];
  #pragma unroll
  for (int fn = 0; fn < 4; ++fn)
    bsv[fn] = bsum[dir * 512 + n0 + wc * 64 + fn * 16 + (lane & 15)];
  #pragma unroll
  for (int fm = 0; fm < 4; ++fm)
    #pragma unroll
    for (int fn = 0; fn < 4; ++fn)
      #pragma unroll
      for (int u = 0; u < 4; ++u) {
        int m = m0 + wr * 64 + fm * 16 + (lane >> 4) * 4 + u;
        int n = n0 + wc * 64 + fn * 16 + (lane & 15);
        xp[((size_t)dir << 25) + (size_t)m * 512 + n] = (_Float16)(acc[fm][fn][u] + bsv[fn]);
      }
}

// ---------------------------------------------------------------------------
// rnn_rec (r10): overflow weights streamed from L2 (VMEM pipe), not LDS.
//   r8 mapping: 512 thr, wave ke = l>>6 (pairs ke*32..+31), lane lv = l&63,
//   j = {4lv..4lv+3} (A) and {256+4lv..} (B).
//   pairs 0..23 resident in regs (192); pairs 24..31 streamed per step from
//   GLOBAL (whT is 1 MB -> L2-resident per XCD; 64 lanes x dwordx4 = 1 KB
//   coalesced). volatile blocks LICM (re-load each step by design);
//   sched_barrier(0x387) = VALU/SALU/DS may cross, VMEM may NOT -> issue
//   points pinned ~3 cb-groups (300-500 cyc) ahead of consumption.
//   LDS pipe/step now only: 64 uniform h-b128 + 48 psum + 4 h-writes.
// ---------------------------------------------------------------------------
__global__ __launch_bounds__(512, 2) void rnn_rec(const _Float16* __restrict__ xp,
                                                  const uint32_t* __restrict__ whT,
                                                  float* __restrict__ out) {
  __shared__ uint32_t hl[256];       // h(t) as 256 f16x2 pairs
  __shared__ float psum[8][512];     // per-k-eighth partials

  const int bid = blockIdx.x;
  const int dir = bid & 1, b = bid >> 1;
  const int l = threadIdx.x;
  const int ke = l >> 6, lv = l & 63;
  const int j0 = lv * 4;

  const uint32_t* wb = whT + dir * (256 * 512) + (ke * 32) * 512 + j0;

  // resident pairs 0..23
  u4 wA[24], wB[24];
  #pragma unroll
  for (int p = 0; p < 24; ++p) {
    wA[p] = *(const u4*)(wb + p * 512);
    wB[p] = *(const u4*)(wb + p * 512 + 256);
  }

  if (l < 256) hl[l] = 0;
  __syncthreads();

  const _Float16* xpp = xp + ((size_t)dir << 25) + ((size_t)b << 19);
  float* op = out + (((size_t)(b * 2 + dir)) << 19);

#define LDA(p)  (*(volatile const u4*)(wb + (p) * 512))
#define LDB(p)  (*(volatile const u4*)(wb + (p) * 512 + 256))
#define FDP(WA, WB, HW)                                   \
  do {                                                    \
    _Pragma("unroll")                                     \
    for (int jj = 0; jj < 4; ++jj) {                      \
      aA[jj] = fdot2((WA)[jj], (HW), aA[jj]);             \
      aB[jj] = fdot2((WB)[jj], (HW), aB[jj]);             \
    }                                                     \
  } while (0)
#define FD4(BASE, HV)                                     \
  do {                                                    \
    _Pragma("unroll")                                     \
    for (int i = 0; i < 4; ++i)                           \
      FDP(wA[(BASE) + i], wB[(BASE) + i], (HV)[i]);       \
  } while (0)

  for (int t = 0; t < TSTEPS; ++t) {
    // xp prefetch for epilogue; fire-and-forget across barriers.
    h2 xv = (h2)(_Float16)0.f;
    if (l < 256) xv = *(const h2*)(xpp + (size_t)t * 512 + 2 * l);

    f4 aA = (f4)0.f, aB = (f4)0.f;
    const uint32_t* hq = hl + ke * 32;

    // ---- stream issue #1: pairs 24,25 (L2) ----
    u4 sA0 = LDA(24), sB0 = LDB(24);
    u4 sA1 = LDA(25), sB1 = LDB(25);
    __builtin_amdgcn_sched_barrier(0x387);

    { u4 hv = *(const u4*)(hq + 0); FD4(0, hv); }     // cb0: pairs 0..3
    { u4 hv = *(const u4*)(hq + 4); FD4(4, hv); }     // cb1: pairs 4..7

    // ---- stream issue #2: pairs 26,27 ----
    u4 sA2 = LDA(26), sB2 = LDB(26);
    u4 sA3 = LDA(27), sB3 = LDB(27);
    __builtin_amdgcn_sched_barrier(0x387);

    { u4 hv = *(const u4*)(hq + 8); FD4(8, hv); }     // cb2: pairs 8..11

    u4 hv6 = *(const u4*)(hq + 24);                   // h for pairs 24..27
    FDP(sA0, sB0, hv6[0]);                            // consume 24
    FDP(sA1, sB1, hv6[1]);                            // consume 25

    // ---- stream issue #3: pairs 28,29 ----
    u4 sA4 = LDA(28), sB4 = LDB(28);
    u4 sA5 = LDA(29), sB5 = LDB(29);
    __builtin_amdgcn_sched_barrier(0x387);

    { u4 hv = *(const u4*)(hq + 12); FD4(12, hv); }   // cb3: pairs 12..15
    FDP(sA2, sB2, hv6[2]);                            // consume 26
    FDP(sA3, sB3, hv6[3]);                            // consume 27

    // ---- stream issue #4: pairs 30,31 ----
    u4 sA6 = LDA(30), sB6 = LDB(30);
    u4 sA7 = LDA(31), sB7 = LDB(31);
    __builtin_amdgcn_sched_barrier(0x387);

    { u4 hv = *(const u4*)(hq + 16); FD4(16, hv); }   // cb4: pairs 16..19
    u4 hv7 = *(const u4*)(hq + 28);                   // h for pairs 28..31
    FDP(sA4, sB4, hv7[0]);                            // consume 28
    FDP(sA5, sB5, hv7[1]);                            // consume 29

    { u4 hv = *(const u4*)(hq + 20); FD4(20, hv); }   // cb5: pairs 20..23
    FDP(sA6, sB6, hv7[2]);                            // consume 30
    FDP(sA7, sB7, hv7[3]);                            // consume 31

    *(f4*)(&psum[ke][j0])       = aA;                 // one b128 write
    *(f4*)(&psum[ke][256 + j0]) = aB;
    BAR_LDS();                                         // B1 (no vmcnt drain)

    if (l < 256) {
      float s0 = (float)xv[0], s1 = (float)xv[1];
      #pragma unroll
      for (int k2 = 0; k2 < 8; ++k2) {
        f2 v = *(const f2*)(&psum[k2][2 * l]);        // ds_read_b64
        s0 += v[0]; s1 += v[1];
      }
      float e0 = __expf(2.f * s0);
      float h0 = 1.f - 2.f * __builtin_amdgcn_rcpf(e0 + 1.f);   // tanh
      float e1 = __expf(2.f * s1);
      float h1 = 1.f - 2.f * __builtin_amdgcn_rcpf(e1 + 1.f);
      f2 o; o[0] = h0; o[1] = h1;
      *(f2*)(op + (size_t)t * 512 + 2 * l) = o;       // coalesced store
      h2 pk; pk[0] = (_Float16)h0; pk[1] = (_Float16)h1;
      hl[l] = __builtin_bit_cast(uint32_t, pk);       // one b32 write
    }
    BAR_LDS();                                         // B2: h(t) ready
  }
#undef LDA
#undef LDB
#undef FDP
#undef FD4
}

// ---------------------------------------------------------------------------
extern "C" void kernel_launch(void* const* d_in, const int* in_sizes, int n_in,
                              void* d_out, int out_size, void* d_ws, size_t ws_size,
                              hipStream_t stream) {
  const float* x     = (const float*)d_in[0];
  const float* Wih_f = (const float*)d_in[1];
  const float* Whh_f = (const float*)d_in[2];
  const float* bih_f = (const float*)d_in[3];
  const float* bhh_f = (const float*)d_in[4];
  const float* Wih_b = (const float*)d_in[5];
  const float* Whh_b = (const float*)d_in[6];
  const float* bih_b = (const float*)d_in[7];
  const float* bhh_b = (const float*)d_in[8];

  char* ws = (char*)d_ws;
  _Float16* xp16 = (_Float16*)ws;                 // 128 MB
  _Float16* wi16 = (_Float16*)(ws + 134217728);   // 1 MB
  uint32_t* whT  = (uint32_t*)(ws + 135266304);   // 1 MB
  float*    bsum = (float*)(ws + 136314880);      // 4 KB
  float* out = (float*)d_out;

  prep_kernel<<<2048, 256, 0, stream>>>(Wih_f, Whh_f, bih_f, bhh_f,
                                        Wih_b, Whh_b, bih_b, bhh_b, wi16, whT, bsum);
  dim3 g(512, 4, 2);
  xp_gemm<<<g, 256, 0, stream>>>(x, wi16, bsum, xp16);

  rnn_rec<<<128, 512, 0, stream>>>(xp16, whT, out);
}

// Round 12
// 1621.177 us; speedup vs baseline: 3.0547x; 3.0547x over previous
//
#include <hip/hip_runtime.h>
#include <hip/hip_fp16.h>
#include <cstdint>

typedef _Float16 h2 __attribute__((ext_vector_type(2)));
typedef _Float16 h8 __attribute__((ext_vector_type(8)));
typedef float    f2 __attribute__((ext_vector_type(2)));
typedef float    f4 __attribute__((ext_vector_type(4)));
typedef uint32_t u4 __attribute__((ext_vector_type(4)));

#define BATCH 64
#define TSTEPS 1024
#define DDIM 512
#define HDIM 512

static __device__ __forceinline__ float fdot2(uint32_t w, uint32_t h, float acc) {
  return __builtin_amdgcn_fdot2(__builtin_bit_cast(h2, w), __builtin_bit_cast(h2, h), acc, false);
}

#define SB0() __builtin_amdgcn_sched_barrier(0)

// Raw barrier: LDS-ordering only — NO vmcnt drain (xp loads / out stores stay
// in flight across barriers). Verified win in r4.
#define BAR_LDS()                                            \
  do {                                                       \
    __builtin_amdgcn_sched_barrier(0);                       \
    asm volatile("s_waitcnt lgkmcnt(0)" ::: "memory");       \
    __builtin_amdgcn_s_barrier();                            \
    __builtin_amdgcn_sched_barrier(0);                       \
  } while (0)

// ---------------------------------------------------------------------------
// prep: f16 weight conversion, pair-transposed Whh, bias sums.
// ---------------------------------------------------------------------------
__global__ void prep_kernel(const float* __restrict__ Wih_f, const float* __restrict__ Whh_f,
                            const float* __restrict__ bih_f, const float* __restrict__ bhh_f,
                            const float* __restrict__ Wih_b, const float* __restrict__ Whh_b,
                            const float* __restrict__ bih_b, const float* __restrict__ bhh_b,
                            _Float16* __restrict__ wi16, uint32_t* __restrict__ whT,
                            float* __restrict__ bsum) {
  int i = blockIdx.x * 256 + threadIdx.x;
  if (i < 2 * 512 * 512) {
    const float* s = (i < 512 * 512) ? Wih_f : Wih_b;
    wi16[i] = (_Float16)s[i & (512 * 512 - 1)];
  }
  if (i < 2 * 256 * 512) {
    int d = i >> 17; int rem = i & ((1 << 17) - 1);
    int kp = rem >> 9; int j = rem & 511;
    const float* W = d ? Whh_b : Whh_f;
    h2 p; p[0] = (_Float16)W[j * 512 + 2 * kp]; p[1] = (_Float16)W[j * 512 + 2 * kp + 1];
    whT[i] = __builtin_bit_cast(uint32_t, p);
  }
  if (i < 2 * 512) {
    int d = i >> 9, j = i & 511;
    bsum[i] = d ? (bih_b[j] + bhh_b[j]) : (bih_f[j] + bhh_f[j]);
  }
}

// ---------------------------------------------------------------------------
// xp_gemm (unchanged): xp[dir][m][n] f16, m = b*1024 + t (processing order).
// ---------------------------------------------------------------------------
__global__ __launch_bounds__(256) void xp_gemm(const float* __restrict__ x,
                                               const _Float16* __restrict__ wi,
                                               const float* __restrict__ bsum,
                                               _Float16* __restrict__ xp) {
  __shared__ _Float16 As[128][40];
  __shared__ _Float16 Bs[128][40];
  const int mt = blockIdx.x, nt = blockIdx.y, dir = blockIdx.z;
  const int m0 = mt * 128, n0 = nt * 128;
  const int tid = threadIdx.x;
  const int lane = tid & 63, w = tid >> 6;
  const int wr = w >> 1, wc = w & 1;
  const int ra = tid >> 1, hf = tid & 1;

  const int mrow = m0 + ra;
  const int bb = mrow >> 10, pp = mrow & 1023;
  const int srow = dir ? ((bb << 10) + (1023 - pp)) : mrow;
  const float*    xbase = x + (size_t)srow * 512 + hf * 16;
  const _Float16* wbase = wi + (size_t)dir * 512 * 512 + (size_t)(n0 + ra) * 512 + hf * 16;

  f4 acc[4][4];
  #pragma unroll
  for (int a = 0; a < 4; ++a)
    #pragma unroll
    for (int b = 0; b < 4; ++b) acc[a][b] = (f4)0.f;

  for (int k0 = 0; k0 < 512; k0 += 32) {
    f4 x0 = *(const f4*)(xbase + k0);
    f4 x1 = *(const f4*)(xbase + k0 + 4);
    f4 x2 = *(const f4*)(xbase + k0 + 8);
    f4 x3 = *(const f4*)(xbase + k0 + 12);
    h8 b0 = *(const h8*)(wbase + k0);
    h8 b1 = *(const h8*)(wbase + k0 + 8);
    h8 a0, a1;
    #pragma unroll
    for (int u = 0; u < 4; ++u) {
      a0[u] = (_Float16)x0[u]; a0[4 + u] = (_Float16)x1[u];
      a1[u] = (_Float16)x2[u]; a1[4 + u] = (_Float16)x3[u];
    }
    __syncthreads();
    *(h8*)&As[ra][hf * 16]     = a0;
    *(h8*)&As[ra][hf * 16 + 8] = a1;
    *(h8*)&Bs[ra][hf * 16]     = b0;
    *(h8*)&Bs[ra][hf * 16 + 8] = b1;
    __syncthreads();
    h8 af[4], bf[4];
    #pragma unroll
    for (int fm = 0; fm < 4; ++fm)
      af[fm] = *(const h8*)&As[wr * 64 + fm * 16 + (lane & 15)][(lane >> 4) * 8];
    #pragma unroll
    for (int fn = 0; fn < 4; ++fn)
      bf[fn] = *(const h8*)&Bs[wc * 64 + fn * 16 + (lane & 15)][(lane >> 4) * 8];
    #pragma unroll
    for (int fm = 0; fm < 4; ++fm)
      #pragma unroll
      for (int fn = 0; fn < 4; ++fn)
        acc[fm][fn] = __builtin_amdgcn_mfma_f32_16x16x32_f16(af[fm], bf[fn], acc[fm][fn], 0, 0, 0);
  }

  float bsv[4];
  #pragma unroll
  for (int fn = 0; fn < 4; ++fn)
    bsv[fn] = bsum[dir * 512 + n0 + wc * 64 + fn * 16 + (lane & 15)];
  #pragma unroll
  for (int fm = 0; fm < 4; ++fm)
    #pragma unroll
    for (int fn = 0; fn < 4; ++fn)
      #pragma unroll
      for (int u = 0; u < 4; ++u) {
        int m = m0 + wr * 64 + fm * 16 + (lane >> 4) * 4 + u;
        int n = n0 + wc * 64 + fn * 16 + (lane & 15);
        xp[((size_t)dir << 25) + (size_t)m * 512 + n] = (_Float16)(acc[fm][fn][u] + bsv[fn]);
      }
}

// ---------------------------------------------------------------------------
// rnn_rec (r11 fixed): r8 base + software-pipelined LDS weight stream.
//   512 thr, wave ke = l>>6 (pairs ke*32..+31), lane lv = l&63,
//   j = {4lv..4lv+3} (A) and {256+4lv..+3} (B).
//   Pairs 0..23 resident in regs (192); pairs 24..31 in LDS (group-contiguous,
//   2 slots/pair: A,B). Streamed reads are issued as named-register prefetches
//   TWO PAIRS (>=64 fdot2 ~ 128+ cyc) ahead of consumption; sched_barrier(0)
//   fences pin issue clusters so the compiler can't sink loads to their uses
//   (the r5-r8 just-in-time pattern left ~40-120 cyc exposed per read).
//   Peak live streamed regs = 2 pairs = 16; 192 + 16 + working ~ 246 <= 256.
// ---------------------------------------------------------------------------
__global__ __launch_bounds__(512, 2) void rnn_rec(const _Float16* __restrict__ xp,
                                                  const uint32_t* __restrict__ whT,
                                                  float* __restrict__ out) {
  extern __shared__ char smem[];
  uint32_t* wl   = (uint32_t*)smem;              // 128 KB: 64 groups x 2048 B
  uint32_t* hl   = (uint32_t*)(smem + 131072);   // h(t): 256 f16x2 pairs
  float*    psum = (float*)(smem + 132096);      // [8][512] flat = 16 KB

  const int bid = blockIdx.x;
  const int dir = bid & 1, b = bid >> 1;
  const int l = threadIdx.x;
  const int ke = l >> 6, lv = l & 63;
  const int j0 = lv * 4;

  const uint32_t* wb = whT + dir * (256 * 512) + (ke * 32) * 512 + j0;

  // resident pairs 0..23
  u4 wA[24], wB[24];
  #pragma unroll
  for (int p = 0; p < 24; ++p) {
    wA[p] = *(const u4*)(wb + p * 512);
    wB[p] = *(const u4*)(wb + p * 512 + 256);
  }

  // LDS pairs 24..31: slot s = (p-24)*2 + half; 8-lane groups own 2048 B.
  char* wlb = (char*)wl + (l >> 3) * 2048 + (l & 7) * 16;
  #pragma unroll
  for (int p = 0; p < 8; ++p) {
    *(u4*)(wlb + (p * 2 + 0) * 128) = *(const u4*)(wb + (24 + p) * 512);
    *(u4*)(wlb + (p * 2 + 1) * 128) = *(const u4*)(wb + (24 + p) * 512 + 256);
  }
  if (l < 256) hl[l] = 0;
  __syncthreads();

  const _Float16* xpp = xp + ((size_t)dir << 25) + ((size_t)b << 19);
  float* op = out + (((size_t)(b * 2 + dir)) << 19);

#define LSA(p) (*(const u4*)(wlb + ((p) - 24) * 256))        // slot A of pair p
#define LSB(p) (*(const u4*)(wlb + ((p) - 24) * 256 + 128))  // slot B of pair p
#define FDP(WA, WB, HW)                                   \
  do {                                                    \
    _Pragma("unroll")                                     \
    for (int jj = 0; jj < 4; ++jj) {                      \
      aA[jj] = fdot2((WA)[jj], (HW), aA[jj]);             \
      aB[jj] = fdot2((WB)[jj], (HW), aB[jj]);             \
    }                                                     \
  } while (0)
#define FD4(BASE, HV)                                     \
  do {                                                    \
    _Pragma("unroll")                                     \
    for (int i = 0; i < 4; ++i)                           \
      FDP(wA[(BASE) + i], wB[(BASE) + i], (HV)[i]);       \
  } while (0)

  for (int t = 0; t < TSTEPS; ++t) {
    // xp prefetch (VMEM, fire-and-forget across barriers)
    h2 xv = (h2)(_Float16)0.f;
    if (l < 256) xv = *(const h2*)(xpp + (size_t)t * 512 + 2 * l);

    f4 aA = (f4)0.f, aB = (f4)0.f;
    const uint32_t* hq = hl + ke * 32;

    // ---- prologue issue: h cb0,cb1 + stream pairs 24,25 ----
    u4 hv0 = *(const u4*)(hq + 0);
    u4 hv1 = *(const u4*)(hq + 4);
    u4 s24A = LSA(24), s24B = LSB(24);
    u4 s25A = LSA(25), s25B = LSB(25);
    SB0();
    FD4(0, hv0);                          // cb0 (32 fdot2)
    u4 hv6 = *(const u4*)(hq + 24);       // h for pairs 24..27
    u4 s26A = LSA(26), s26B = LSB(26);
    SB0();
    FD4(4, hv1);                          // cb1
    u4 s27A = LSA(27), s27B = LSB(27);
    SB0();
    FDP(s24A, s24B, hv6[0]);              // consume pair 24
    FDP(s25A, s25B, hv6[1]);              // consume pair 25
    u4 hv2 = *(const u4*)(hq + 8);
    u4 s28A = LSA(28), s28B = LSB(28);
    SB0();
    FD4(8, hv2);                          // cb2
    u4 s29A = LSA(29), s29B = LSB(29);
    SB0();
    FDP(s26A, s26B, hv6[2]);              // consume pair 26
    FDP(s27A, s27B, hv6[3]);              // consume pair 27
    u4 hv3 = *(const u4*)(hq + 12);
    u4 hv7 = *(const u4*)(hq + 28);       // h for pairs 28..31
    u4 s30A = LSA(30), s30B = LSB(30);
    SB0();
    FD4(12, hv3);                         // cb3
    u4 s31A = LSA(31), s31B = LSB(31);
    SB0();
    FDP(s28A, s28B, hv7[0]);              // consume pair 28
    FDP(s29A, s29B, hv7[1]);              // consume pair 29
    u4 hv4 = *(const u4*)(hq + 16);
    SB0();
    FD4(16, hv4);                         // cb4
    u4 hv5 = *(const u4*)(hq + 20);
    SB0();
    FDP(s30A, s30B, hv7[2]);              // consume pair 30
    FDP(s31A, s31B, hv7[3]);              // consume pair 31
    SB0();
    FD4(20, hv5);                         // cb5

    *(f4*)(psum + ke * 512 + j0)       = aA;    // one b128 write each
    *(f4*)(psum + ke * 512 + 256 + j0) = aB;
    BAR_LDS();                             // B1 (no vmcnt drain)

    if (l < 256) {
      float s0 = (float)xv[0], s1 = (float)xv[1];
      #pragma unroll
      for (int k2 = 0; k2 < 8; ++k2) {
        f2 v = *(const f2*)(psum + k2 * 512 + 2 * l);   // ds_read_b64
        s0 += v[0]; s1 += v[1];
      }
      float e0 = __expf(2.f * s0);
      float h0 = 1.f - 2.f * __builtin_amdgcn_rcpf(e0 + 1.f);   // tanh
      float e1 = __expf(2.f * s1);
      float h1 = 1.f - 2.f * __builtin_amdgcn_rcpf(e1 + 1.f);
      f2 o; o[0] = h0; o[1] = h1;
      *(f2*)(op + (size_t)t * 512 + 2 * l) = o;  // coalesced store
      h2 pk; pk[0] = (_Float16)h0; pk[1] = (_Float16)h1;
      hl[l] = __builtin_bit_cast(uint32_t, pk);  // one b32 write
    }
    BAR_LDS();                             // B2: h(t) ready
  }
#undef LSA
#undef LSB
#undef FDP
#undef FD4
}

// ---------------------------------------------------------------------------
extern "C" void kernel_launch(void* const* d_in, const int* in_sizes, int n_in,
                              void* d_out, int out_size, void* d_ws, size_t ws_size,
                              hipStream_t stream) {
  const float* x     = (const float*)d_in[0];
  const float* Wih_f = (const float*)d_in[1];
  const float* Whh_f = (const float*)d_in[2];
  const float* bih_f = (const float*)d_in[3];
  const float* bhh_f = (const float*)d_in[4];
  const float* Wih_b = (const float*)d_in[5];
  const float* Whh_b = (const float*)d_in[6];
  const float* bih_b = (const float*)d_in[7];
  const float* bhh_b = (const float*)d_in[8];

  char* ws = (char*)d_ws;
  _Float16* xp16 = (_Float16*)ws;                 // 128 MB
  _Float16* wi16 = (_Float16*)(ws + 134217728);   // 1 MB
  uint32_t* whT  = (uint32_t*)(ws + 135266304);   // 1 MB
  float*    bsum = (float*)(ws + 136314880);      // 4 KB
  float* out = (float*)d_out;

  prep_kernel<<<2048, 256, 0, stream>>>(Wih_f, Whh_f, bih_f, bhh_f,
                                        Wih_b, Whh_b, bih_b, bhh_b, wi16, whT, bsum);
  dim3 g(512, 4, 2);
  xp_gemm<<<g, 256, 0, stream>>>(x, wi16, bsum, xp16);

  const int REC_LDS = 148480;  // 128K wl + 1K hl + 16K psum
  (void)hipFuncSetAttribute((const void*)rnn_rec, hipFuncAttributeMaxDynamicSharedMemorySize, REC_LDS);
  rnn_rec<<<128, 512, REC_LDS, stream>>>(xp16, whT, out);
}